// Round 8
// baseline (16.449 us; speedup 1.0000x reference)
//
#include <hip/hip_runtime.h>
#include <math.h>

#define NB   8
#define NC   2048
#define HH   128
#define WW   128
#define NTQ  4096
#define EPSF 1e-6f
#define CELLW 0.125f
#define BLK  512
#define QPB  64          // queries per block, 8 lanes per query
#define LPQ  8
#define CAP  16          // bucket capacity per cell (mean occupancy 8)
#define SPCAP 256        // spill capacity (expected spill ~1-2 pts/block)
#define UMAX 0xFFFFFFFFFFFFFFFFULL

typedef unsigned long long u64;

// branchless top-3 insert under u64 = (d2_bits<<32)|orig_idx lexicographic order
__device__ __forceinline__ void ins3u(u64 u, u64& U0, u64& U1, u64& U2) {
    bool lt2 = u < U2, lt1 = u < U1, lt0 = u < U0;
    U2 = lt1 ? U1 : (lt2 ? u : U2);
    U1 = lt0 ? U0 : (lt1 ? u : U1);
    U0 = lt0 ? u  : U0;
}

__global__ __launch_bounds__(BLK, 4) void fused_interp_kernel(
    const float* __restrict__ xc_off,  // (B,NC,2)
    const float* __restrict__ yc_off,  // (B,NC,1)
    const float* __restrict__ xc_on,   // (B,H,W,2)
    const float* __restrict__ yc_on,   // (B,H,W,1)
    const float* __restrict__ xt,      // (B,NT,2)
    const float* __restrict__ mw,      // (2,1)
    const float* __restrict__ mb,      // (1,)
    float* __restrict__ out)           // (B,NT,1)
{
#pragma clang fp contract(off)
    __shared__ float2 sxy[256 * CAP];   // 32 KB: bucketed point coords
    __shared__ int    sidx[256 * CAP];  // 16 KB: bucketed original indices
    __shared__ int    scnt[256];        // per-cell count (may exceed CAP)
    __shared__ float2 spxy[SPCAP];      // spill coords
    __shared__ int    spidx[SPCAP];     // spill indices
    __shared__ int    sspill;
    __shared__ float  sgx[HH];
    __shared__ float  sgy[WW];
    __shared__ float  sred[8];

    const int tid   = threadIdx.x;
    const int bid   = blockIdx.x;
    const int b     = bid & 7;            // XCD-aware: batch b lives on one XCD's L2
    const int qbase = (bid >> 3) * QPB;   // 64 blocks per batch

    // ---- zero counters + stage grid axes (one pre-barrier phase)
    if (tid < 256) scnt[tid] = 0;
    if (tid == 0) sspill = 0;
    const float* xob = xc_on + (size_t)b * HH * WW * 2;
    if (tid >= 256 && tid < 256 + HH) sgx[tid - 256] = xob[(size_t)(tid - 256) * (WW * 2)];
    if (tid >= 384 && tid < 384 + WW) sgy[tid - 384] = xob[2 * (tid - 384) + 1];
    __syncthreads();

    // ---- capacity-bucket build: one atomic + one write per point, no scan pass
    const float2* xcb = (const float2*)(xc_off + (size_t)b * NC * 2);
    const float*  ycb = yc_off + (size_t)b * NC;
    float vsum = 0.f;
#pragma unroll
    for (int t = 0; t < 4; ++t) {
        int k = tid + t * BLK;
        float2 P = xcb[k];
        vsum += ycb[k];
        int cx = min(max((int)floorf((P.x + 1.0f) * 8.0f), 0), 15);
        int cy = min(max((int)floorf((P.y + 1.0f) * 8.0f), 0), 15);
        int c = cy * 16 + cx;
        int slot = atomicAdd(&scnt[c], 1);
        if (slot < CAP) {
            sxy[c * CAP + slot] = P;
            sidx[c * CAP + slot] = k;
        } else {
            int sp = atomicAdd(&sspill, 1);
            if (sp < SPCAP) { spxy[sp] = P; spidx[sp] = k; }
        }
    }
    for (int o = 32; o > 0; o >>= 1) vsum += __shfl_down(vsum, o);
    if ((tid & 63) == 0) sred[tid >> 6] = vsum;
    __syncthreads();

    // ---- 8-lane-per-query search, fully unrolled predicated 3x3 scan
    const int g   = tid & (LPQ - 1);
    const int grp = tid >> 3;             // 0..63
    const int q   = qbase + grp;
    const float2 Q = ((const float2*)xt)[(size_t)b * NTQ + q];
    const float qx = Q.x, qy = Q.y;
    const int qcx = min(max((int)floorf((qx + 1.0f) * 8.0f), 0), 15);
    const int qcy = min(max((int)floorf((qy + 1.0f) * 8.0f), 0), 15);

    // 9 cell bases + clamped counts (OOB cells get count 0)
    int cbase[9], ccnt[9];
#pragma unroll
    for (int i = 0; i < 9; ++i) {
        int cx = qcx + (i % 3) - 1, cy = qcy + (i / 3) - 1;
        bool ok = (cx >= 0) && (cx <= 15) && (cy >= 0) && (cy <= 15);
        int c = ok ? (cy * 16 + cx) : 0;
        cbase[i] = c * CAP;
        ccnt[i]  = ok ? min(scnt[c], CAP) : 0;
    }

    u64 P0 = UMAX, P1 = UMAX, P2 = UMAX;
    u64 F0 = UMAX, F1 = UMAX, F2 = UMAX;

    // static 18-iteration scan: slot = g + 8h in each of 9 cells (disjoint per lane)
#pragma unroll
    for (int i = 0; i < 9; ++i) {
#pragma unroll
        for (int h = 0; h < 2; ++h) {
            int slot = g + 8 * h;
            bool valid = slot < ccnt[i];
            int a = cbase[i] + slot;
            float2 P = sxy[a];
            int   id = sidx[a];
            float dx = qx - P.x, dy = qy - P.y;
            float dd = dx * dx + dy * dy;       // mul,mul,add — contract off
            u64 u = valid ? (((u64)__float_as_uint(dd) << 32) | (unsigned int)id) : UMAX;
            ins3u(u, F0, F1, F2);
        }
    }
    // spill list (usually empty); scanning extra points never corrupts a total-order top-3
    {
        int ns = min(sspill, SPCAP);
        for (int k = g; k < ns; k += LPQ) {
            float2 P = spxy[k];
            int   id = spidx[k];
            float dx = qx - P.x, dy = qy - P.y;
            float dd = dx * dx + dy * dy;
            u64 u = ((u64)__float_as_uint(dd) << 32) | (unsigned int)id;
            ins3u(u, F0, F1, F2);
        }
    }
    // butterfly merge across the 8 lanes (disjoint sets each round)
    for (int m = 1; m <= 4; m <<= 1) {
        u64 e0 = __shfl_xor(F0, m), e1 = __shfl_xor(F1, m), e2 = __shfl_xor(F2, m);
        ins3u(e0, F0, F1, F2);
        ins3u(e1, F0, F1, F2);
        ins3u(e2, F0, F1, F2);
    }
    P0 = F0; P1 = F1; P2 = F2;

    float bnd = 1.0f * CELLW - 1e-6f;   // unscanned bucketed cells are ring>=2
    u64 thr = ((u64)__float_as_uint(bnd * bnd)) << 32;
    bool done = P2 < thr;

    // exactness-guard ring expansion (statistically ~never taken)
    for (int r = 2; r <= 15; ++r) {
        if (__all(done)) break;
        if (!done) {                  // group-uniform (P identical across the 8 lanes)
            F0 = F1 = F2 = UMAX;
            for (int t = g; t < 8 * r; t += LPQ) {
                int side = t / (2 * r), u = t % (2 * r);
                int dx, dy;
                if (side == 0)      { dx = -r + u; dy = -r; }
                else if (side == 1) { dx = r;      dy = -r + u; }
                else if (side == 2) { dx = r - u;  dy = r; }
                else                { dx = -r;     dy = r - u; }
                int cx = qcx + dx, cy = qcy + dy;
                if (cx < 0 || cx > 15 || cy < 0 || cy > 15) continue;
                int c = cy * 16 + cx;
                int cnt = min(scnt[c], CAP);
                for (int s = 0; s < cnt; ++s) {
                    float2 P = sxy[c * CAP + s];
                    int   id = sidx[c * CAP + s];
                    float ddx = qx - P.x, ddy = qy - P.y;
                    float dd = ddx * ddx + ddy * ddy;
                    u64 uu = ((u64)__float_as_uint(dd) << 32) | (unsigned int)id;
                    ins3u(uu, F0, F1, F2);
                }
            }
            for (int m = 1; m <= 4; m <<= 1) {
                u64 e0 = __shfl_xor(F0, m), e1 = __shfl_xor(F1, m), e2 = __shfl_xor(F2, m);
                ins3u(e0, F0, F1, F2);
                ins3u(e1, F0, F1, F2);
                ins3u(e2, F0, F1, F2);
            }
            ins3u(F0, P0, P1, P2);
            ins3u(F1, P0, P1, P2);
            ins3u(F2, P0, P1, P2);
            float bb = (float)r * CELLW - 1e-6f;
            u64 tt = ((u64)__float_as_uint(bb * bb)) << 32;
            done = P2 < tt;
        }
    }

    // ---- in-group epilogue on lane g==0: gathers spread across all 8 waves
    if (g == 0) {
        const float fillv = (sred[0] + sred[1] + sred[2] + sred[3] +
                             sred[4] + sred[5] + sred[6] + sred[7]) / (float)NC;
        const int J0 = (int)(P0 & 0xFFFFFFFFULL);
        const int J1 = (int)(P1 & 0xFFFFFFFFULL);
        const int J2 = (int)(P2 & 0xFFFFFFFFULL);

        float2 A  = xcb[J0];
        float2 Bp = xcb[J1];
        float2 C  = xcb[J2];
        float e1x = Bp.x - A.x, e1y = Bp.y - A.y;
        float e2x = C.x  - A.x, e2y = C.y  - A.y;
        float rx  = qx - A.x,   ry  = qy - A.y;
        float det = e1x * e2y - e1y * e2x;
        float adet = fabsf(det);
        float dets = (adet < EPSF) ? 1.0f : det;
        float w1 = (rx * e2y - ry * e2x) / dets;
        float w2 = (e1x * ry - e1y * rx) / dets;
        float w0 = 1.0f - w1 - w2;
        bool inside = (w0 >= -EPSF) && (w1 >= -EPSF) && (w2 >= -EPSF) && (adet >= EPSF);
        float interp = w0 * ycb[J0] + w1 * ycb[J1] + w2 * ycb[J2];
        float yoff = inside ? interp : fillv;

        // on-grid bilinear (searchsorted: ix = clip(ss-1, 0, H-2); fix-up vs LDS axes)
        int ix = (int)((qx + 1.0f) * 63.5f);
        ix = min(max(ix, 0), HH - 2);
        while (ix > 0 && !(sgx[ix] < qx)) --ix;
        while (ix < HH - 2 && sgx[ix + 1] < qx) ++ix;
        int iy = (int)((qy + 1.0f) * 63.5f);
        iy = min(max(iy, 0), WW - 2);
        while (iy > 0 && !(sgy[iy] < qy)) --iy;
        while (iy < WW - 2 && sgy[iy + 1] < qy) ++iy;

        float x0 = sgx[ix], x1 = sgx[ix + 1];
        float y0 = sgy[iy], y1 = sgy[iy + 1];
        float tx = (qx - x0) / (x1 - x0);
        float ty = (qy - y0) / (y1 - y0);
        const float* yob = yc_on + (size_t)b * HH * WW;
        float v00 = yob[ix * WW + iy];
        float v01 = yob[ix * WW + iy + 1];
        float v10 = yob[(ix + 1) * WW + iy];
        float v11 = yob[(ix + 1) * WW + iy + 1];
        float yon = v00 * (1.f - tx) * (1.f - ty)
                  + v10 * tx * (1.f - ty)
                  + v01 * (1.f - tx) * ty
                  + v11 * tx * ty;
        // xt in [-1,1), grid spans [-1,1] -> on-grid fill path unreachable

        out[(size_t)b * NTQ + q] = yoff * mw[0] + yon * mw[1] + mb[0];
    }
}

extern "C" void kernel_launch(void* const* d_in, const int* in_sizes, int n_in,
                              void* d_out, int out_size, void* d_ws, size_t ws_size,
                              hipStream_t stream) {
    const float* xc_off = (const float*)d_in[0];
    const float* yc_off = (const float*)d_in[1];
    const float* xc_on  = (const float*)d_in[2];
    const float* yc_on  = (const float*)d_in[3];
    const float* xt     = (const float*)d_in[4];
    const float* mix_w  = (const float*)d_in[5];
    const float* mix_b  = (const float*)d_in[6];
    float* out = (float*)d_out;

    fused_interp_kernel<<<NB * (NTQ / QPB), BLK, 0, stream>>>(   // 512 blocks
        xc_off, yc_off, xc_on, yc_on, xt, mix_w, mix_b, out);
}

// Round 9
// 13.663 us; speedup vs baseline: 1.2039x; 1.2039x over previous
//
#include <hip/hip_runtime.h>
#include <math.h>

#define NB   8
#define NC   2048
#define HH   128
#define WW   128
#define NTQ  4096
#define EPSF 1e-6f
#define CELLW 0.125f
#define BLK  512
#define QPB  128         // queries per block, 4 lanes per query
#define LPQ  4
#define UMAX 0xFFFFFFFFFFFFFFFFULL
#define FMAXV 3.402823466e+38f

typedef unsigned long long u64;

// branchless top-3 insert under u64 = (d2_bits<<32)|orig_idx lexicographic order
__device__ __forceinline__ void ins3u(u64 u, u64& U0, u64& U1, u64& U2) {
    bool lt2 = u < U2, lt1 = u < U1, lt0 = u < U0;
    U2 = lt1 ? U1 : (lt2 ? u : U2);
    U1 = lt0 ? U0 : (lt1 ? u : U1);
    U0 = lt0 ? u  : U0;
}

__global__ __launch_bounds__(BLK) void fused_interp_kernel(
    const float* __restrict__ xc_off,  // (B,NC,2)
    const float* __restrict__ yc_off,  // (B,NC,1)
    const float* __restrict__ xc_on,   // (B,H,W,2)
    const float* __restrict__ yc_on,   // (B,H,W,1)
    const float* __restrict__ xt,      // (B,NT,2)
    const float* __restrict__ mw,      // (2,1)
    const float* __restrict__ mb,      // (1,)
    float* __restrict__ out)           // (B,NT,1)
{
#pragma clang fp contract(off)
    __shared__ float4 spts[NC];      // 32 KB: (x, y, val, orig_idx bits), CSR order
    __shared__ int    shist[256];
    __shared__ int    soffs[257];
    __shared__ int    scur[256];
    __shared__ float  sgx[HH];
    __shared__ float  sgy[WW];
    __shared__ float  sred[8];

    const int tid   = threadIdx.x;
    const int b     = blockIdx.x >> 5;           // 32 blocks per batch
    const int qbase = (blockIdx.x & 31) * QPB;

    // ---- zero hist + stage grid axes
    if (tid < 256) shist[tid] = 0;
    const float* xob = xc_on + (size_t)b * HH * WW * 2;
    if (tid >= 256 && tid < 256 + HH) sgx[tid - 256] = xob[(size_t)(tid - 256) * (WW * 2)];
    if (tid >= 384 && tid < 384 + WW) sgy[tid - 384] = xob[2 * (tid - 384) + 1];
    __syncthreads();

    // ---- read context, histogram cells, partial value-sum
    const float2* xcb = (const float2*)(xc_off + (size_t)b * NC * 2);
    const float*  ycb = yc_off + (size_t)b * NC;
    float2 pp_[4]; float vv_[4]; int cc_[4];
    float vsum = 0.f;
#pragma unroll
    for (int t = 0; t < 4; ++t) {
        int k = tid + t * BLK;
        float2 P = xcb[k];
        float  V = ycb[k];
        pp_[t] = P; vv_[t] = V;
        int cx = (int)floorf((P.x + 1.0f) * 8.0f); cx = min(max(cx, 0), 15);
        int cy = (int)floorf((P.y + 1.0f) * 8.0f); cy = min(max(cy, 0), 15);
        cc_[t] = cy * 16 + cx;
        atomicAdd(&shist[cc_[t]], 1);
        vsum += V;
    }
    for (int o = 32; o > 0; o >>= 1) vsum += __shfl_down(vsum, o);
    if ((tid & 63) == 0) sred[tid >> 6] = vsum;
    __syncthreads();

    // ---- wave 0: exclusive scan of 256 cell counts
    if (tid < 64) {
        int h0 = shist[4*tid], h1 = shist[4*tid+1], h2 = shist[4*tid+2], h3 = shist[4*tid+3];
        int s = h0 + h1 + h2 + h3; int tot = s;
        for (int off = 1; off < 64; off <<= 1) {
            int u = __shfl_up(s, off);
            if (tid >= off) s += u;
        }
        int excl = s - tot;
        soffs[4*tid]   = excl;
        soffs[4*tid+1] = excl + h0;
        soffs[4*tid+2] = excl + h0 + h1;
        soffs[4*tid+3] = excl + h0 + h1 + h2;
        if (tid == 63) soffs[256] = excl + tot;   // == NC
    }
    __syncthreads();
    if (tid < 256) scur[tid] = soffs[tid];
    __syncthreads();

    // ---- scatter into CSR order in LDS
#pragma unroll
    for (int t = 0; t < 4; ++t) {
        int k = tid + t * BLK;
        int pos = atomicAdd(&scur[cc_[t]], 1);
        float4 o4; o4.x = pp_[t].x; o4.y = pp_[t].y; o4.z = vv_[t]; o4.w = __int_as_float(k);
        spts[pos] = o4;
    }
    __syncthreads();

    const float fillv = (sred[0] + sred[1] + sred[2] + sred[3] +
                         sred[4] + sred[5] + sred[6] + sred[7]) / (float)NC;

    // ---- 4-lane-per-query search: 2x2 nearest cell box + exact coverage guard
    const int g   = tid & (LPQ - 1);
    const int grp = tid >> 2;         // 0..127
    const int q   = qbase + grp;
    const float2 Q = ((const float2*)xt)[(size_t)b * NTQ + q];
    const float qx = Q.x, qy = Q.y;
    const int qcx = min(max((int)floorf((qx + 1.0f) * 8.0f), 0), 15);
    const int qcy = min(max((int)floorf((qy + 1.0f) * 8.0f), 0), 15);

    // nearest 2x2 box: cell + neighbor toward the query's half of the cell
    const float fx = (qx + 1.0f) - (float)qcx * CELLW;   // in [0, 0.125)
    const float fy = (qy + 1.0f) - (float)qcy * CELLW;
    const int bx0 = qcx + ((fx > 0.0625f) ? 0 : -1);
    const int by0 = qcy + ((fy > 0.0625f) ? 0 : -1);
    const int bxl = max(bx0, 0), bxh = min(bx0 + 1, 15);
    const int byl = max(by0, 0), byh = min(by0 + 1, 15);
    // exact covered radius: distance to box outer edges; domain-edge => inf
    const float xlo = -1.0f + (float)bx0 * CELLW, xhi = xlo + 0.25f;
    const float ylo = -1.0f + (float)by0 * CELLW, yhi = ylo + 0.25f;
    const float dxl = (bx0 <= 0)  ? FMAXV : (qx - xlo);
    const float dxr = (bx0 >= 14) ? FMAXV : (xhi - qx);
    const float dyl = (by0 <= 0)  ? FMAXV : (qy - ylo);
    const float dyh = (by0 >= 14) ? FMAXV : (yhi - qy);
    const float rcov = fminf(fminf(dxl, dxr), fminf(dyl, dyh));

    u64 P0 = UMAX, P1 = UMAX, P2 = UMAX;
    u64 F0 = UMAX, F1 = UMAX, F2 = UMAX;

    // box rows are contiguous CSR segments; lanes stride over points
    for (int row = byl; row <= byh; ++row) {
        int s = soffs[row * 16 + bxl], e = soffs[row * 16 + bxh + 1];
        for (int k = s + g; k < e; k += LPQ) {
            float4 P = spts[k];
            float dx = qx - P.x, dy = qy - P.y;
            float dd = dx * dx + dy * dy;          // mul,mul,add — contract off
            u64 u = ((u64)__float_as_uint(dd) << 32) | (unsigned int)__float_as_int(P.w);
            ins3u(u, F0, F1, F2);
        }
    }
    // butterfly merge across the 4 lanes (disjoint sets each round)
    for (int m = 1; m <= 2; m <<= 1) {
        u64 e0 = __shfl_xor(F0, m), e1 = __shfl_xor(F1, m), e2 = __shfl_xor(F2, m);
        ins3u(e0, F0, F1, F2);
        ins3u(e1, F0, F1, F2);
        ins3u(e2, F0, F1, F2);
    }
    P0 = F0; P1 = F1; P2 = F2;

    {
        float t = fmaxf(rcov - 1e-6f, 0.0f);
        u64 thr = ((u64)__float_as_uint(t * t)) << 32;
        bool done = P2 < thr;

        if (!__all(done)) {
            // ---- fallback 1 (~1% of queries): complete the 3x3 ring-0..1
            // scan only cells NOT in the box (duplicates would corrupt top-3)
            if (!done) {              // group-uniform (P identical across lanes)
                F0 = F1 = F2 = UMAX;
                int my = (by0 == qcy - 1) ? qcy + 1 : qcy - 1;  // missing row
                int mx = (bx0 == qcx - 1) ? qcx + 1 : qcx - 1;  // missing col
                if (my >= 0 && my <= 15) {
                    int c0 = my * 16 + max(qcx - 1, 0);
                    int c1 = my * 16 + min(qcx + 1, 15);
                    int s = soffs[c0], e = soffs[c1 + 1];
                    for (int k = s + g; k < e; k += LPQ) {
                        float4 P = spts[k];
                        float dx = qx - P.x, dy = qy - P.y;
                        float dd = dx * dx + dy * dy;
                        u64 u = ((u64)__float_as_uint(dd) << 32) | (unsigned int)__float_as_int(P.w);
                        ins3u(u, F0, F1, F2);
                    }
                }
                if (mx >= 0 && mx <= 15) {
                    for (int row = byl; row <= byh; ++row) {
                        int c = row * 16 + mx;
                        int s = soffs[c], e = soffs[c + 1];
                        for (int k = s + g; k < e; k += LPQ) {
                            float4 P = spts[k];
                            float dx = qx - P.x, dy = qy - P.y;
                            float dd = dx * dx + dy * dy;
                            u64 u = ((u64)__float_as_uint(dd) << 32) | (unsigned int)__float_as_int(P.w);
                            ins3u(u, F0, F1, F2);
                        }
                    }
                }
                for (int m = 1; m <= 2; m <<= 1) {
                    u64 e0 = __shfl_xor(F0, m), e1 = __shfl_xor(F1, m), e2 = __shfl_xor(F2, m);
                    ins3u(e0, F0, F1, F2);
                    ins3u(e1, F0, F1, F2);
                    ins3u(e2, F0, F1, F2);
                }
                ins3u(F0, P0, P1, P2);
                ins3u(F1, P0, P1, P2);
                ins3u(F2, P0, P1, P2);
                float bb = CELLW - 1e-6f;
                u64 tt = ((u64)__float_as_uint(bb * bb)) << 32;
                done = P2 < tt;
            }

            // ---- fallback 2: exactness-guard ring expansion (~never taken)
            for (int r = 2; r <= 15; ++r) {
                if (__all(done)) break;
                if (!done) {
                    F0 = F1 = F2 = UMAX;
                    for (int t = g; t < 8 * r; t += LPQ) {
                        int side = t / (2 * r), u = t % (2 * r);
                        int dx, dy;
                        if (side == 0)      { dx = -r + u; dy = -r; }
                        else if (side == 1) { dx = r;      dy = -r + u; }
                        else if (side == 2) { dx = r - u;  dy = r; }
                        else                { dx = -r;     dy = r - u; }
                        int cx = qcx + dx, cy = qcy + dy;
                        if (cx < 0 || cx > 15 || cy < 0 || cy > 15) continue;
                        int c = cy * 16 + cx;
                        int s = soffs[c], e = soffs[c + 1];
                        for (int k = s; k < e; ++k) {
                            float4 P = spts[k];
                            float ddx = qx - P.x, ddy = qy - P.y;
                            float dd = ddx * ddx + ddy * ddy;
                            u64 uu = ((u64)__float_as_uint(dd) << 32) | (unsigned int)__float_as_int(P.w);
                            ins3u(uu, F0, F1, F2);
                        }
                    }
                    for (int m = 1; m <= 2; m <<= 1) {
                        u64 e0 = __shfl_xor(F0, m), e1 = __shfl_xor(F1, m), e2 = __shfl_xor(F2, m);
                        ins3u(e0, F0, F1, F2);
                        ins3u(e1, F0, F1, F2);
                        ins3u(e2, F0, F1, F2);
                    }
                    ins3u(F0, P0, P1, P2);
                    ins3u(F1, P0, P1, P2);
                    ins3u(F2, P0, P1, P2);
                    float bb = (float)r * CELLW - 1e-6f;
                    u64 tt = ((u64)__float_as_uint(bb * bb)) << 32;
                    done = P2 < tt;
                }
            }
        }
    }

    // ---- epilogue on lane g==0 (triangle coords re-read from global, L2-hot)
    if (g == 0) {
        int J0 = (int)(P0 & 0xFFFFFFFFULL);
        int J1 = (int)(P1 & 0xFFFFFFFFULL);
        int J2 = (int)(P2 & 0xFFFFFFFFULL);
        float2 A  = xcb[J0];
        float2 Bp = xcb[J1];
        float2 C  = xcb[J2];
        float e1x = Bp.x - A.x, e1y = Bp.y - A.y;
        float e2x = C.x  - A.x, e2y = C.y  - A.y;
        float rx  = qx - A.x,   ry  = qy - A.y;
        float det = e1x * e2y - e1y * e2x;
        float adet = fabsf(det);
        float dets = (adet < EPSF) ? 1.0f : det;
        float w1 = (rx * e2y - ry * e2x) / dets;
        float w2 = (e1x * ry - e1y * rx) / dets;
        float w0 = 1.0f - w1 - w2;
        bool inside = (w0 >= -EPSF) && (w1 >= -EPSF) && (w2 >= -EPSF) && (adet >= EPSF);
        float interp = w0 * ycb[J0] + w1 * ycb[J1] + w2 * ycb[J2];
        float yoff = inside ? interp : fillv;

        // on-grid bilinear (searchsorted: ix = clip(ss-1, 0, H-2); fix-up vs LDS axes)
        int ix = (int)((qx + 1.0f) * 63.5f);
        ix = min(max(ix, 0), HH - 2);
        while (ix > 0 && !(sgx[ix] < qx)) --ix;
        while (ix < HH - 2 && sgx[ix + 1] < qx) ++ix;
        int iy = (int)((qy + 1.0f) * 63.5f);
        iy = min(max(iy, 0), WW - 2);
        while (iy > 0 && !(sgy[iy] < qy)) --iy;
        while (iy < WW - 2 && sgy[iy + 1] < qy) ++iy;

        float x0 = sgx[ix], x1 = sgx[ix + 1];
        float y0 = sgy[iy], y1 = sgy[iy + 1];
        float tx = (qx - x0) / (x1 - x0);
        float ty = (qy - y0) / (y1 - y0);
        const float* yob = yc_on + (size_t)b * HH * WW;
        float v00 = yob[ix * WW + iy];
        float v01 = yob[ix * WW + iy + 1];
        float v10 = yob[(ix + 1) * WW + iy];
        float v11 = yob[(ix + 1) * WW + iy + 1];
        float yon = v00 * (1.f - tx) * (1.f - ty)
                  + v10 * tx * (1.f - ty)
                  + v01 * (1.f - tx) * ty
                  + v11 * tx * ty;
        // xt in [-1,1), grid spans [-1,1] -> on-grid fill path unreachable

        out[(size_t)b * NTQ + q] = yoff * mw[0] + yon * mw[1] + mb[0];
    }
}

extern "C" void kernel_launch(void* const* d_in, const int* in_sizes, int n_in,
                              void* d_out, int out_size, void* d_ws, size_t ws_size,
                              hipStream_t stream) {
    const float* xc_off = (const float*)d_in[0];
    const float* yc_off = (const float*)d_in[1];
    const float* xc_on  = (const float*)d_in[2];
    const float* yc_on  = (const float*)d_in[3];
    const float* xt     = (const float*)d_in[4];
    const float* mix_w  = (const float*)d_in[5];
    const float* mix_b  = (const float*)d_in[6];
    float* out = (float*)d_out;

    fused_interp_kernel<<<NB * (NTQ / QPB), BLK, 0, stream>>>(   // 256 blocks
        xc_off, yc_off, xc_on, yc_on, xt, mix_w, mix_b, out);
}

// Round 10
// 12.430 us; speedup vs baseline: 1.3233x; 1.0992x over previous
//
#include <hip/hip_runtime.h>
#include <math.h>

#define NB   8
#define NC   2048
#define HH   128
#define WW   128
#define NTQ  4096
#define EPSF 1e-6f
#define CELLW 0.125f
#define BLK  512
#define QPB  128         // queries per block, 4 lanes per query
#define LPQ  4
#define UMAX 0xFFFFFFFFFFFFFFFFULL

typedef unsigned long long u64;

// branchless top-3 insert under u64 = (d2_bits<<32)|orig_idx lexicographic order
__device__ __forceinline__ void ins3u(u64 u, u64& U0, u64& U1, u64& U2) {
    bool lt2 = u < U2, lt1 = u < U1, lt0 = u < U0;
    U2 = lt1 ? U1 : (lt2 ? u : U2);
    U1 = lt0 ? U0 : (lt1 ? u : U1);
    U0 = lt0 ? u  : U0;
}

__global__ __launch_bounds__(BLK) void fused_interp_kernel(
    const float* __restrict__ xc_off,  // (B,NC,2)
    const float* __restrict__ yc_off,  // (B,NC,1)
    const float* __restrict__ xc_on,   // (B,H,W,2)
    const float* __restrict__ yc_on,   // (B,H,W,1)
    const float* __restrict__ xt,      // (B,NT,2)
    const float* __restrict__ mw,      // (2,1)
    const float* __restrict__ mb,      // (1,)
    float* __restrict__ out)           // (B,NT,1)
{
#pragma clang fp contract(off)
    __shared__ float4 spts[NC];      // 32 KB: (x, y, val, orig_idx bits), CSR order
    __shared__ int    shist[256];
    __shared__ int    soffs[257];
    __shared__ int    scur[256];
    __shared__ float  sgx[HH];
    __shared__ float  sgy[WW];
    __shared__ float  sred[8];

    const int tid   = threadIdx.x;
    const int b     = blockIdx.x >> 5;           // 32 blocks per batch
    const int qbase = (blockIdx.x & 31) * QPB;

    // ---- zero hist + stage grid axes
    if (tid < 256) shist[tid] = 0;
    const float* xob = xc_on + (size_t)b * HH * WW * 2;
    if (tid >= 256 && tid < 256 + HH) sgx[tid - 256] = xob[(size_t)(tid - 256) * (WW * 2)];
    if (tid >= 384 && tid < 384 + WW) sgy[tid - 384] = xob[2 * (tid - 384) + 1];
    __syncthreads();

    // ---- stage 4 consecutive points/thread via float4; histogram; value-sum
    const float4* xc4 = (const float4*)(xc_off + (size_t)b * NC * 2);  // 1024 float4
    const float4* yc4 = (const float4*)(yc_off + (size_t)b * NC);     // 512 float4
    const float4 pA = xc4[2 * tid];        // points 4t, 4t+1
    const float4 pB = xc4[2 * tid + 1];    // points 4t+2, 4t+3
    const float4 vv = yc4[tid];            // values 4t..4t+3
    float px_[4] = { pA.x, pA.z, pB.x, pB.z };
    float py_[4] = { pA.y, pA.w, pB.y, pB.w };
    float vl_[4] = { vv.x, vv.y, vv.z, vv.w };
    int   cc_[4];
    float vsum = vv.x + vv.y + vv.z + vv.w;
#pragma unroll
    for (int t = 0; t < 4; ++t) {
        // x in [-1,1): (x+1)*8 in [0,16] after rounding -> trunc, clamp high only
        int cx = min((int)((px_[t] + 1.0f) * 8.0f), 15);
        int cy = min((int)((py_[t] + 1.0f) * 8.0f), 15);
        cc_[t] = cy * 16 + cx;
        atomicAdd(&shist[cc_[t]], 1);
    }
    for (int o = 32; o > 0; o >>= 1) vsum += __shfl_down(vsum, o);
    if ((tid & 63) == 0) sred[tid >> 6] = vsum;
    __syncthreads();

    // ---- wave 0: exclusive scan of 256 cell counts (writes soffs AND scur)
    if (tid < 64) {
        int h0 = shist[4*tid], h1 = shist[4*tid+1], h2 = shist[4*tid+2], h3 = shist[4*tid+3];
        int s = h0 + h1 + h2 + h3; int tot = s;
        for (int off = 1; off < 64; off <<= 1) {
            int u = __shfl_up(s, off);
            if (tid >= off) s += u;
        }
        int excl = s - tot;
        int o0 = excl, o1 = excl + h0, o2 = excl + h0 + h1, o3 = excl + h0 + h1 + h2;
        soffs[4*tid]   = o0;  scur[4*tid]   = o0;
        soffs[4*tid+1] = o1;  scur[4*tid+1] = o1;
        soffs[4*tid+2] = o2;  scur[4*tid+2] = o2;
        soffs[4*tid+3] = o3;  scur[4*tid+3] = o3;
        if (tid == 63) soffs[256] = excl + tot;   // == NC
    }
    __syncthreads();

    // ---- scatter into CSR order in LDS
#pragma unroll
    for (int t = 0; t < 4; ++t) {
        int k = 4 * tid + t;
        int pos = atomicAdd(&scur[cc_[t]], 1);
        float4 o4; o4.x = px_[t]; o4.y = py_[t]; o4.z = vl_[t]; o4.w = __int_as_float(k);
        spts[pos] = o4;
    }
    __syncthreads();

    const float fillv = (sred[0] + sred[1] + sred[2] + sred[3] +
                         sred[4] + sred[5] + sred[6] + sred[7]) / (float)NC;

    // ---- 4-lane-per-query search; candidates from LDS, balanced over points
    const int g   = tid & (LPQ - 1);
    const int grp = tid >> 2;         // 0..127
    const int q   = qbase + grp;
    const float2 Q = ((const float2*)xt)[(size_t)b * NTQ + q];
    const float qx = Q.x, qy = Q.y;
    const int qcx = min((int)((qx + 1.0f) * 8.0f), 15);
    const int qcy = min((int)((qy + 1.0f) * 8.0f), 15);

    u64 P0 = UMAX, P1 = UMAX, P2 = UMAX;   // persistent top-3
    u64 F0 = UMAX, F1 = UMAX, F2 = UMAX;   // fresh candidates

    // rings 0..1: three contiguous CSR row-segments, lanes stride over points
    for (int row = 0; row < 3; ++row) {
        int cy = qcy + row - 1;
        if (cy < 0 || cy > 15) continue;
        int c0 = cy * 16 + max(qcx - 1, 0);
        int c1 = cy * 16 + min(qcx + 1, 15);
        int s = soffs[c0], e = soffs[c1 + 1];
        for (int k = s + g; k < e; k += LPQ) {
            float4 P = spts[k];
            float dx = qx - P.x, dy = qy - P.y;
            float dd = dx * dx + dy * dy;          // mul,mul,add — contract off
            u64 u = ((u64)__float_as_uint(dd) << 32) | (unsigned int)__float_as_int(P.w);
            ins3u(u, F0, F1, F2);
        }
    }
    // butterfly merge across the 4 lanes (disjoint sets each round)
    for (int m = 1; m <= 2; m <<= 1) {
        u64 e0 = __shfl_xor(F0, m), e1 = __shfl_xor(F1, m), e2 = __shfl_xor(F2, m);
        ins3u(e0, F0, F1, F2);
        ins3u(e1, F0, F1, F2);
        ins3u(e2, F0, F1, F2);
    }
    P0 = F0; P1 = F1; P2 = F2;

    float bnd = 1.0f * CELLW - 1e-6f;
    u64 thr = ((u64)__float_as_uint(bnd * bnd)) << 32;
    bool done = P2 < thr;

    // exactness-guard ring expansion (statistically ~never taken)
    for (int r = 2; r <= 15; ++r) {
        if (__all(done)) break;
        if (!done) {                  // group-uniform (P identical across the 4 lanes)
            F0 = F1 = F2 = UMAX;
            for (int t = g; t < 8 * r; t += LPQ) {
                int side = t / (2 * r), u = t % (2 * r);
                int dx, dy;
                if (side == 0)      { dx = -r + u; dy = -r; }
                else if (side == 1) { dx = r;      dy = -r + u; }
                else if (side == 2) { dx = r - u;  dy = r; }
                else                { dx = -r;     dy = r - u; }
                int cx = qcx + dx, cy = qcy + dy;
                if (cx < 0 || cx > 15 || cy < 0 || cy > 15) continue;
                int c = cy * 16 + cx;
                int s = soffs[c], e = soffs[c + 1];
                for (int k = s; k < e; ++k) {
                    float4 P = spts[k];
                    float ddx = qx - P.x, ddy = qy - P.y;
                    float dd = ddx * ddx + ddy * ddy;
                    u64 uu = ((u64)__float_as_uint(dd) << 32) | (unsigned int)__float_as_int(P.w);
                    ins3u(uu, F0, F1, F2);
                }
            }
            for (int m = 1; m <= 2; m <<= 1) {
                u64 e0 = __shfl_xor(F0, m), e1 = __shfl_xor(F1, m), e2 = __shfl_xor(F2, m);
                ins3u(e0, F0, F1, F2);
                ins3u(e1, F0, F1, F2);
                ins3u(e2, F0, F1, F2);
            }
            ins3u(F0, P0, P1, P2);
            ins3u(F1, P0, P1, P2);
            ins3u(F2, P0, P1, P2);
            float bb = (float)r * CELLW - 1e-6f;
            u64 tt = ((u64)__float_as_uint(bb * bb)) << 32;
            done = P2 < tt;
        }
    }

    // ---- epilogue on lane g==0 (triangle data from LDS-free global, L2-hot)
    if (g == 0) {
        const float2* xcb = (const float2*)(xc_off + (size_t)b * NC * 2);
        const float*  ycb = yc_off + (size_t)b * NC;
        int J0 = (int)(P0 & 0xFFFFFFFFULL);
        int J1 = (int)(P1 & 0xFFFFFFFFULL);
        int J2 = (int)(P2 & 0xFFFFFFFFULL);
        float2 A  = xcb[J0];
        float2 Bp = xcb[J1];
        float2 C  = xcb[J2];
        float e1x = Bp.x - A.x, e1y = Bp.y - A.y;
        float e2x = C.x  - A.x, e2y = C.y  - A.y;
        float rx  = qx - A.x,   ry  = qy - A.y;
        float det = e1x * e2y - e1y * e2x;
        float adet = fabsf(det);
        float dets = (adet < EPSF) ? 1.0f : det;
        float w1 = (rx * e2y - ry * e2x) / dets;
        float w2 = (e1x * ry - e1y * rx) / dets;
        float w0 = 1.0f - w1 - w2;
        bool inside = (w0 >= -EPSF) && (w1 >= -EPSF) && (w2 >= -EPSF) && (adet >= EPSF);
        float interp = w0 * ycb[J0] + w1 * ycb[J1] + w2 * ycb[J2];
        float yoff = inside ? interp : fillv;

        // on-grid bilinear (searchsorted: ix = clip(ss-1, 0, H-2); fix-up vs LDS axes)
        int ix = (int)((qx + 1.0f) * 63.5f);
        ix = min(max(ix, 0), HH - 2);
        while (ix > 0 && !(sgx[ix] < qx)) --ix;
        while (ix < HH - 2 && sgx[ix + 1] < qx) ++ix;
        int iy = (int)((qy + 1.0f) * 63.5f);
        iy = min(max(iy, 0), WW - 2);
        while (iy > 0 && !(sgy[iy] < qy)) --iy;
        while (iy < WW - 2 && sgy[iy + 1] < qy) ++iy;

        float x0 = sgx[ix], x1 = sgx[ix + 1];
        float y0 = sgy[iy], y1 = sgy[iy + 1];
        float tx = (qx - x0) / (x1 - x0);
        float ty = (qy - y0) / (y1 - y0);
        const float* yob = yc_on + (size_t)b * HH * WW;
        float v00 = yob[ix * WW + iy];
        float v01 = yob[ix * WW + iy + 1];
        float v10 = yob[(ix + 1) * WW + iy];
        float v11 = yob[(ix + 1) * WW + iy + 1];
        float yon = v00 * (1.f - tx) * (1.f - ty)
                  + v10 * tx * (1.f - ty)
                  + v01 * (1.f - tx) * ty
                  + v11 * tx * ty;
        // xt in [-1,1), grid spans [-1,1] -> on-grid fill path unreachable

        out[(size_t)b * NTQ + q] = yoff * mw[0] + yon * mw[1] + mb[0];
    }
}

extern "C" void kernel_launch(void* const* d_in, const int* in_sizes, int n_in,
                              void* d_out, int out_size, void* d_ws, size_t ws_size,
                              hipStream_t stream) {
    const float* xc_off = (const float*)d_in[0];
    const float* yc_off = (const float*)d_in[1];
    const float* xc_on  = (const float*)d_in[2];
    const float* yc_on  = (const float*)d_in[3];
    const float* xt     = (const float*)d_in[4];
    const float* mix_w  = (const float*)d_in[5];
    const float* mix_b  = (const float*)d_in[6];
    float* out = (float*)d_out;

    fused_interp_kernel<<<NB * (NTQ / QPB), BLK, 0, stream>>>(   // 256 blocks
        xc_off, yc_off, xc_on, yc_on, xt, mix_w, mix_b, out);
}